// Round 14
// baseline (356.219 us; speedup 1.0000x reference)
//
#include <hip/hip_runtime.h>

#define N_NODES 100000
#define N_EDGES 1600000
#define N_GRAPHS 1000

#define NB_C 782                 // coarse buckets: dst>>7, 128 nodes each
#define B1   256                 // blocks in count/scatter phases
#define CHUNK (N_EDGES / B1)     // 6250 (exact)
#define MTOT (NB_C * B1)         // 200192 count-matrix entries

#define LSTR 68   // LDS row stride for fp32 tiles (2-way max aliasing = free)
#define GEMM_BLK ((N_NODES + 63) / 64)   // 1563

typedef unsigned int uint32;
typedef unsigned short ushort16;

// float -> bf16 with round-to-nearest-even
static __device__ __forceinline__ ushort16 f2bf(float f) {
    uint32 u = __float_as_uint(f);
    u += 0x7fffu + ((u >> 16) & 1u);
    return (ushort16)(u >> 16);
}
static __device__ __forceinline__ uint32 pk2(float a, float b) {
    return (uint32)f2bf(a) | ((uint32)f2bf(b) << 16);
}
// unpack a bf16x2 word into two floats (lo = even channel, hi = odd channel)
static __device__ __forceinline__ void bf2x(uint32 v, float& lo, float& hi) {
    lo = __uint_as_float(v << 16);
    hi = __uint_as_float(v & 0xffff0000u);
}

// ============ MERGED: layer-1 GEMM (blocks < GEMM_BLK) + dst histogram ============
// The two roles are independent (gemm reads x/W1, count reads dst); merging
// hides the ~10us count under the ~44us gemm and removes one dispatch gap.
__global__ __launch_bounds__(256) void gemm1_count_kernel(
    const float* __restrict__ h,   // [N, 128] fp32 (x)
    const float* __restrict__ W,   // [128, 64] row-major (W1)
    ushort16* __restrict__ y,      // [N, 64] bf16
    const int* __restrict__ dst,   // [E]
    int* __restrict__ M)           // [MTOT] count matrix
{
    __shared__ __align__(16) char smem[64 * LSTR * 4 + 64 * 64 * 4];
    const int t = threadIdx.x;

    if (blockIdx.x >= GEMM_BLK) {
        // ---- count role ----
        int* cnt = (int*)smem;
        int b = blockIdx.x - GEMM_BLK;
        for (int q = t; q < NB_C; q += 256) cnt[q] = 0;
        __syncthreads();
        int e0 = b * CHUNK;
        for (int e = e0 + t; e < e0 + CHUNK; e += 256)
            atomicAdd(&cnt[dst[e] >> 7], 1);
        __syncthreads();
        for (int q = t; q < NB_C; q += 256) M[q * B1 + b] = cnt[q];
        return;
    }

    // ---- gemm role (identical to the measured-best R12 kernel, IN=128) ----
    float* hs  = (float*)smem;                       // [row][k], padded
    float* wsh = (float*)(smem + 64 * LSTR * 4);     // [k][j], native

    const int node0 = blockIdx.x * 64;
    const int m = t >> 4;
    const int p = t & 15;

    float4 acc[4];
#pragma unroll
    for (int i = 0; i < 4; ++i) acc[i] = make_float4(0.f, 0.f, 0.f, 0.f);

    for (int kb = 0; kb < 2; ++kb) {
        if (kb) __syncthreads();
        {
            int kc = (t & 15) * 4;
            int rbase = t >> 4;
#pragma unroll
            for (int rr = 0; rr < 4; ++rr) {
                int row = rr * 16 + rbase;
                int node = node0 + row;
                float4 v = make_float4(0.f, 0.f, 0.f, 0.f);
                if (node < N_NODES)
                    v = *(const float4*)&h[(size_t)node * 128 + kb * 64 + kc];
                *(float4*)&hs[row * LSTR + kc] = v;
            }
        }
        {
            int j4 = (t & 15) * 4;
            int kbase = t >> 4;
#pragma unroll
            for (int it = 0; it < 4; ++it) {
                int k = it * 16 + kbase;
                *(float4*)&wsh[k * 64 + j4] =
                    *(const float4*)&W[(size_t)(kb * 64 + k) * 64 + j4];
            }
        }
        __syncthreads();

        const float* hb = &hs[(m * 4) * LSTR];
#pragma unroll 4
        for (int kc = 0; kc < 64; kc += 4) {
            float4 hv[4];
#pragma unroll
            for (int i = 0; i < 4; ++i) hv[i] = *(const float4*)&hb[i * LSTR + kc];
            float4 w0 = *(const float4*)&wsh[(kc + 0) * 64 + p * 4];
            float4 w1 = *(const float4*)&wsh[(kc + 1) * 64 + p * 4];
            float4 w2 = *(const float4*)&wsh[(kc + 2) * 64 + p * 4];
            float4 w3 = *(const float4*)&wsh[(kc + 3) * 64 + p * 4];
#pragma unroll
            for (int i = 0; i < 4; ++i) {
                acc[i].x = fmaf(hv[i].x, w0.x, acc[i].x);
                acc[i].y = fmaf(hv[i].x, w0.y, acc[i].y);
                acc[i].z = fmaf(hv[i].x, w0.z, acc[i].z);
                acc[i].w = fmaf(hv[i].x, w0.w, acc[i].w);
                acc[i].x = fmaf(hv[i].y, w1.x, acc[i].x);
                acc[i].y = fmaf(hv[i].y, w1.y, acc[i].y);
                acc[i].z = fmaf(hv[i].y, w1.z, acc[i].z);
                acc[i].w = fmaf(hv[i].y, w1.w, acc[i].w);
                acc[i].x = fmaf(hv[i].z, w2.x, acc[i].x);
                acc[i].y = fmaf(hv[i].z, w2.y, acc[i].y);
                acc[i].z = fmaf(hv[i].z, w2.z, acc[i].z);
                acc[i].w = fmaf(hv[i].z, w2.w, acc[i].w);
                acc[i].x = fmaf(hv[i].w, w3.x, acc[i].x);
                acc[i].y = fmaf(hv[i].w, w3.y, acc[i].y);
                acc[i].z = fmaf(hv[i].w, w3.z, acc[i].z);
                acc[i].w = fmaf(hv[i].w, w3.w, acc[i].w);
            }
        }
    }

#pragma unroll
    for (int i = 0; i < 4; ++i) {
        int node = node0 + m * 4 + i;
        if (node >= N_NODES) continue;
        *(uint2*)&y[(size_t)node * 64 + p * 4] =
            make_uint2(pk2(acc[i].x, acc[i].y), pk2(acc[i].z, acc[i].w));
    }
}

#define SCAN_B 1024
#define SCAN_NBLK ((MTOT + SCAN_B - 1) / SCAN_B)   // 196

__global__ __launch_bounds__(256) void scanA_kernel(
    const int* __restrict__ in, int* __restrict__ excl, int* __restrict__ bsum)
{
    __shared__ int s[256];
    int b = blockIdx.x, t = threadIdx.x;
    int base = b * SCAN_B + t * 4;
    int v[4];
#pragma unroll
    for (int i = 0; i < 4; ++i) v[i] = (base + i < MTOT) ? in[base + i] : 0;
    int tsum = v[0] + v[1] + v[2] + v[3];
    s[t] = tsum;
    __syncthreads();
    for (int off = 1; off < 256; off <<= 1) {
        int x = (t >= off) ? s[t - off] : 0;
        __syncthreads();
        s[t] += x;
        __syncthreads();
    }
    int run = s[t] - tsum;
#pragma unroll
    for (int i = 0; i < 4; ++i) {
        if (base + i < MTOT) excl[base + i] = run;
        run += v[i];
    }
    if (t == 255) bsum[b] = s[255];
}

// merged scanB+scanC: every block redundantly scans the 196 partials in LDS
// (196 loads, trivial), then applies its own offset to its segment.
__global__ __launch_bounds__(256) void scanBC_kernel(
    const int* __restrict__ excl, const int* __restrict__ bsum,
    int* __restrict__ out)
{
    __shared__ int s[256];
    int b = blockIdx.x, t = threadIdx.x;
    int v = (t < SCAN_NBLK) ? bsum[t] : 0;
    s[t] = v;
    __syncthreads();
    for (int off = 1; off < 256; off <<= 1) {
        int x = (t >= off) ? s[t - off] : 0;
        __syncthreads();
        s[t] += x;
        __syncthreads();
    }
    // exclusive prefix for this block
    int add = s[b] - bsum[b];
    int base = b * SCAN_B + t * 4;
#pragma unroll
    for (int i = 0; i < 4; ++i)
        if (base + i < MTOT) out[base + i] = excl[base + i] + add;
}

__global__ __launch_bounds__(256) void scatter_kernel(
    const int* __restrict__ src, const int* __restrict__ dst,
    const int* __restrict__ Ms, uint32* __restrict__ tmp)
{
    __shared__ int cur[NB_C];
    int b = blockIdx.x, t = threadIdx.x;
    for (int q = t; q < NB_C; q += 256) cur[q] = Ms[q * B1 + b];
    __syncthreads();
    int e0 = b * CHUNK;
    for (int e = e0 + t; e < e0 + CHUNK; e += 256) {
        int d = dst[e];
        int q = d >> 7;
        int pos = atomicAdd(&cur[q], 1);
        tmp[pos] = ((uint32)(d & 127) << 17) | (uint32)src[e];
    }
}

__global__ __launch_bounds__(256) void finalize_kernel(
    const uint32* __restrict__ tmp, const int* __restrict__ Ms,
    int* __restrict__ row_off, int* __restrict__ esrc)
{
    __shared__ int cnt[128];
    __shared__ int pref[128];
    __shared__ int cur[128];
    int q = blockIdx.x, t = threadIdx.x;
    int start = Ms[q * B1];
    int end = (q == NB_C - 1) ? N_EDGES : Ms[(q + 1) * B1];

    if (t < 128) cnt[t] = 0;
    __syncthreads();
    for (int e = start + t; e < end; e += 256)
        atomicAdd(&cnt[tmp[e] >> 17], 1);
    __syncthreads();
    if (t < 128) pref[t] = cnt[t];
    __syncthreads();
    for (int off = 1; off < 128; off <<= 1) {
        int x = 0;
        if (t < 128 && t >= off) x = pref[t - off];
        __syncthreads();
        if (t < 128) pref[t] += x;
        __syncthreads();
    }
    if (t < 128) {
        int excl = pref[t] - cnt[t];
        int node = q * 128 + t;
        if (node < N_NODES) row_off[node] = start + excl;
        cur[t] = start + excl;
    }
    if (q == 0 && t == 0) row_off[N_NODES] = N_EDGES;
    __syncthreads();
    for (int e = start + t; e < end; e += 256) {
        uint32 u = tmp[e];
        int pos = atomicAdd(&cur[u >> 17], 1);
        esrc[pos] = (int)(u & 0x1FFFFu);
    }
}

// ============ y(bf16) = h(bf16) @ W  — layers 2/3 (R12 internals) ============
__global__ __launch_bounds__(256) void gemm_bf16_kernel(
    const uint32* __restrict__ hb,  // [N, 32] bf16x2 words
    const float* __restrict__ W,    // [64, 64] row-major
    ushort16* __restrict__ y)       // [N, 64] bf16
{
    __shared__ float hs[64 * LSTR];
    __shared__ float wsh[64 * 64];

    const int t = threadIdx.x;
    const int node0 = blockIdx.x * 64;

    // ---- stage h tile from bf16 (unpack at staging) ----
    {
        int w = t & 7;
        int rbase = t >> 3;               // 0..31
#pragma unroll
        for (int rr = 0; rr < 2; ++rr) {
            int row = rr * 32 + rbase;
            int node = node0 + row;
            uint4 v = make_uint4(0u, 0u, 0u, 0u);
            if (node < N_NODES)
                v = *(const uint4*)&hb[(size_t)node * 32 + w * 4];
            float f[8];
            bf2x(v.x, f[0], f[1]);
            bf2x(v.y, f[2], f[3]);
            bf2x(v.z, f[4], f[5]);
            bf2x(v.w, f[6], f[7]);
            float* o = &hs[row * LSTR + w * 8];
            *(float4*)o       = make_float4(f[0], f[1], f[2], f[3]);
            *(float4*)(o + 4) = make_float4(f[4], f[5], f[6], f[7]);
        }
    }
    // ---- stage W tile ----
    {
        int j4 = (t & 15) * 4;
        int kbase = t >> 4;
#pragma unroll
        for (int it = 0; it < 4; ++it) {
            int k = it * 16 + kbase;
            *(float4*)&wsh[k * 64 + j4] = *(const float4*)&W[(size_t)k * 64 + j4];
        }
    }
    __syncthreads();

    const int m = t >> 4;
    const int p = t & 15;
    float4 acc[4];
#pragma unroll
    for (int i = 0; i < 4; ++i) acc[i] = make_float4(0.f, 0.f, 0.f, 0.f);

    const float* hbp = &hs[(m * 4) * LSTR];
#pragma unroll 4
    for (int kc = 0; kc < 64; kc += 4) {
        float4 hv[4];
#pragma unroll
        for (int i = 0; i < 4; ++i) hv[i] = *(const float4*)&hbp[i * LSTR + kc];
        float4 w0 = *(const float4*)&wsh[(kc + 0) * 64 + p * 4];
        float4 w1 = *(const float4*)&wsh[(kc + 1) * 64 + p * 4];
        float4 w2 = *(const float4*)&wsh[(kc + 2) * 64 + p * 4];
        float4 w3 = *(const float4*)&wsh[(kc + 3) * 64 + p * 4];
#pragma unroll
        for (int i = 0; i < 4; ++i) {
            acc[i].x = fmaf(hv[i].x, w0.x, acc[i].x);
            acc[i].y = fmaf(hv[i].x, w0.y, acc[i].y);
            acc[i].z = fmaf(hv[i].x, w0.z, acc[i].z);
            acc[i].w = fmaf(hv[i].x, w0.w, acc[i].w);
            acc[i].x = fmaf(hv[i].y, w1.x, acc[i].x);
            acc[i].y = fmaf(hv[i].y, w1.y, acc[i].y);
            acc[i].z = fmaf(hv[i].y, w1.z, acc[i].z);
            acc[i].w = fmaf(hv[i].y, w1.w, acc[i].w);
            acc[i].x = fmaf(hv[i].z, w2.x, acc[i].x);
            acc[i].y = fmaf(hv[i].z, w2.y, acc[i].y);
            acc[i].z = fmaf(hv[i].z, w2.z, acc[i].z);
            acc[i].w = fmaf(hv[i].z, w2.w, acc[i].w);
            acc[i].x = fmaf(hv[i].w, w3.x, acc[i].x);
            acc[i].y = fmaf(hv[i].w, w3.y, acc[i].y);
            acc[i].z = fmaf(hv[i].w, w3.z, acc[i].z);
            acc[i].w = fmaf(hv[i].w, w3.w, acc[i].w);
        }
    }

#pragma unroll
    for (int i = 0; i < 4; ++i) {
        int node = node0 + m * 4 + i;
        if (node >= N_NODES) continue;
        *(uint2*)&y[(size_t)node * 64 + p * 4] =
            make_uint2(pk2(acc[i].x, acc[i].y), pk2(acc[i].z, acc[i].w));
    }
}

// ============ CSR gather-sum + fused GIN epilogue -> h(bf16) ============
// Wave = 4 nodes. Lane l: g = l>>4 (node), j = (l>>3)&1 (edge slot),
// w = l&7 (uint4 chunk of the 128 B row). 16 gathers in flight per wave;
// single shfl_xor(8) reduction; epilogue once per wave for 4 nodes.
__global__ __launch_bounds__(256) void aggregate_kernel(
    const uint32* __restrict__ y,      // [N, 32] bf16x2 words
    const int* __restrict__ row_off,   // [N+1]
    const int* __restrict__ esrc,      // [E]
    const float* __restrict__ b,       // [64]
    const float* __restrict__ eps_p,   // [1]
    uint32* __restrict__ outb)         // [N, 32] bf16x2 words
{
    int lane = threadIdx.x & 63;
    int wave = threadIdx.x >> 6;
    int g = lane >> 4;        // node sub-index 0..3
    int j = (lane >> 3) & 1;  // edge slot
    int w = lane & 7;         // 16B chunk of row
    int node = blockIdx.x * 16 + wave * 4 + g;   // grid covers N exactly

    int s0 = row_off[node], s1 = row_off[node + 1];
    float a[8], c[8];
#pragma unroll
    for (int i = 0; i < 8; ++i) { a[i] = 0.f; c[i] = 0.f; }

    const uint32* yw = y + (size_t)w * 4;
    int e = s0 + j;
    for (; e + 2 < s1; e += 4) {
        int i0 = esrc[e];
        int i1 = esrc[e + 2];
        uint4 v0 = *(const uint4*)&yw[(size_t)i0 * 32];
        uint4 v1 = *(const uint4*)&yw[(size_t)i1 * 32];
        float lo, hi;
        bf2x(v0.x, lo, hi); a[0] += lo; a[1] += hi;
        bf2x(v0.y, lo, hi); a[2] += lo; a[3] += hi;
        bf2x(v0.z, lo, hi); a[4] += lo; a[5] += hi;
        bf2x(v0.w, lo, hi); a[6] += lo; a[7] += hi;
        bf2x(v1.x, lo, hi); c[0] += lo; c[1] += hi;
        bf2x(v1.y, lo, hi); c[2] += lo; c[3] += hi;
        bf2x(v1.z, lo, hi); c[4] += lo; c[5] += hi;
        bf2x(v1.w, lo, hi); c[6] += lo; c[7] += hi;
    }
    if (e < s1) {
        int i0 = esrc[e];
        uint4 v0 = *(const uint4*)&yw[(size_t)i0 * 32];
        float lo, hi;
        bf2x(v0.x, lo, hi); a[0] += lo; a[1] += hi;
        bf2x(v0.y, lo, hi); a[2] += lo; a[3] += hi;
        bf2x(v0.z, lo, hi); a[4] += lo; a[5] += hi;
        bf2x(v0.w, lo, hi); a[6] += lo; a[7] += hi;
    }
#pragma unroll
    for (int i = 0; i < 8; ++i) {
        a[i] += c[i];
        a[i] += __shfl_xor(a[i], 8);   // combine the two slots (j)
    }

    if (j == 0) {
        uint4 sv = *(const uint4*)&yw[(size_t)node * 32];
        float s[8];
        bf2x(sv.x, s[0], s[1]);
        bf2x(sv.y, s[2], s[3]);
        bf2x(sv.z, s[4], s[5]);
        bf2x(sv.w, s[6], s[7]);
        float ep1 = 1.0f + eps_p[0];
        float4 b0 = *(const float4*)&b[w * 8];
        float4 b1 = *(const float4*)&b[w * 8 + 4];
        float r0 = fmaxf(fmaf(ep1, s[0], a[0]) + b0.x, 0.0f);
        float r1 = fmaxf(fmaf(ep1, s[1], a[1]) + b0.y, 0.0f);
        float r2 = fmaxf(fmaf(ep1, s[2], a[2]) + b0.z, 0.0f);
        float r3 = fmaxf(fmaf(ep1, s[3], a[3]) + b0.w, 0.0f);
        float r4 = fmaxf(fmaf(ep1, s[4], a[4]) + b1.x, 0.0f);
        float r5 = fmaxf(fmaf(ep1, s[5], a[5]) + b1.y, 0.0f);
        float r6 = fmaxf(fmaf(ep1, s[6], a[6]) + b1.z, 0.0f);
        float r7 = fmaxf(fmaf(ep1, s[7], a[7]) + b1.w, 0.0f);
        *(uint4*)&outb[(size_t)node * 32 + w * 4] =
            make_uint4(pk2(r0, r1), pk2(r2, r3), pk2(r4, r5), pk2(r6, r7));
    }
}

// ============ mean-pool (sorted batch, binary search, bf16 h) + head MLP ============
__global__ __launch_bounds__(256) void pool_head_kernel(
    const uint32* __restrict__ hb,    // [N, 32] bf16x2 words
    const int* __restrict__ batch,    // [N], sorted
    const float* __restrict__ Wf,     // [64, 10]
    const float* __restrict__ bfv,    // [10]
    const float* __restrict__ Wl,     // [10]
    const float* __restrict__ blv,    // [1]
    float* __restrict__ out)          // [G]
{
    __shared__ float red[4][64];
    __shared__ float pooled[64];
    __shared__ float hid[10];
    int g = blockIdx.x;
    int t = threadIdx.x;
    int lo = 0, hi = N_NODES;
    while (lo < hi) { int mid = (lo + hi) >> 1; if (batch[mid] < g) lo = mid + 1; else hi = mid; }
    int start = lo;
    hi = N_NODES;
    while (lo < hi) { int mid = (lo + hi) >> 1; if (batch[mid] < g + 1) lo = mid + 1; else hi = mid; }
    int end = lo;

    int c = t & 63, nl = t >> 6;
    int wd = c >> 1, odd = c & 1;
    float acc = 0.0f;
    for (int i = start + nl; i < end; i += 4) {
        uint32 u = hb[(size_t)i * 32 + wd];
        acc += __uint_as_float(odd ? (u & 0xffff0000u) : (u << 16));
    }
    red[nl][c] = acc;
    __syncthreads();
    if (t < 64) {
        float cnt = (float)(end - start);
        float inv = 1.0f / fmaxf(cnt, 1.0f);
        pooled[t] = (red[0][t] + red[1][t] + red[2][t] + red[3][t]) * inv;
    }
    __syncthreads();
    if (t < 10) {
        float s = bfv[t];
#pragma unroll
        for (int k = 0; k < 64; ++k) s = fmaf(pooled[k], Wf[k * 10 + t], s);
        hid[t] = fmaxf(s, 0.0f);
    }
    __syncthreads();
    if (t == 0) {
        float s = blv[0];
#pragma unroll
        for (int j = 0; j < 10; ++j) s = fmaf(hid[j], Wl[j], s);
        out[g] = s;
    }
}

extern "C" void kernel_launch(void* const* d_in, const int* in_sizes, int n_in,
                              void* d_out, int out_size, void* d_ws, size_t ws_size,
                              hipStream_t stream)
{
    const float* x     = (const float*)d_in[0];
    const int*   ei    = (const int*)  d_in[1];
    const int*   src   = ei;               // edge_index[0]
    const int*   dst   = ei + N_EDGES;     // edge_index[1]
    const int*   batch = (const int*)  d_in[2];
    const float* W1    = (const float*)d_in[3];
    const float* b1    = (const float*)d_in[4];
    const float* W2    = (const float*)d_in[5];
    const float* b2    = (const float*)d_in[6];
    const float* W3    = (const float*)d_in[7];
    const float* b3    = (const float*)d_in[8];
    const float* Wf    = (const float*)d_in[9];
    const float* bfv   = (const float*)d_in[10];
    const float* Wl    = (const float*)d_in[11];
    const float* blv   = (const float*)d_in[12];
    const float* eps1  = (const float*)d_in[13];
    const float* eps2  = (const float*)d_in[14];
    const float* eps3  = (const float*)d_in[15];

    // ---- workspace layout (two ping-pong bf16 node arrays) ----
    ushort16* ybA = (ushort16*)d_ws;                       // N*64 bf16
    ushort16* ybB = ybA + (size_t)N_NODES * 64;            // N*64 bf16
    int*   ints = (int*)(ybB + (size_t)N_NODES * 64);
    int*   M       = ints;                      // MTOT
    int*   Mex     = M + MTOT;                  // MTOT
    int*   Ms      = Mex + MTOT;                // MTOT
    int*   bsum    = Ms + MTOT;                 // 256
    int*   row_off = bsum + 256;                // N+1
    int*   esrc    = row_off + N_NODES + 1;     // E
    uint32* tmp    = (uint32*)(esrc + N_EDGES); // E

    const int agg_blk = N_NODES / 16;            // 6250 (exact: 16 nodes/block)

    // ---- dispatch 1: layer-1 GEMM + dst histogram (independent, merged) ----
    gemm1_count_kernel<<<GEMM_BLK + B1, 256, 0, stream>>>(x, W1, ybA, dst, M);

    // ---- CSR build (scan merged B+C) ----
    scanA_kernel<<<SCAN_NBLK, 256, 0, stream>>>(M, Mex, bsum);
    scanBC_kernel<<<SCAN_NBLK, 256, 0, stream>>>(Mex, bsum, Ms);
    scatter_kernel<<<B1, 256, 0, stream>>>(src, dst, Ms, tmp);
    finalize_kernel<<<NB_C, 256, 0, stream>>>(tmp, Ms, row_off, esrc);

    // ---- layer 1 aggregate: h1 = GIN(y1) (ybB, bf16) ----
    aggregate_kernel<<<agg_blk, 256, 0, stream>>>(
        (const uint32*)ybA, row_off, esrc, b1, eps1, (uint32*)ybB);

    // ---- layer 2 ----
    gemm_bf16_kernel<<<GEMM_BLK, 256, 0, stream>>>((const uint32*)ybB, W2, ybA);
    aggregate_kernel<<<agg_blk, 256, 0, stream>>>(
        (const uint32*)ybA, row_off, esrc, b2, eps2, (uint32*)ybB);

    // ---- layer 3 ----
    gemm_bf16_kernel<<<GEMM_BLK, 256, 0, stream>>>((const uint32*)ybB, W3, ybA);
    aggregate_kernel<<<agg_blk, 256, 0, stream>>>(
        (const uint32*)ybA, row_off, esrc, b3, eps3, (uint32*)ybB);

    // ---- pool + head ----
    pool_head_kernel<<<N_GRAPHS, 256, 0, stream>>>(
        (const uint32*)ybB, batch, Wf, bfv, Wl, blv, (float*)d_out);
}

// Round 15
// 352.725 us; speedup vs baseline: 1.0099x; 1.0099x over previous
//
#include <hip/hip_runtime.h>

#define N_NODES 100000
#define N_EDGES 1600000
#define N_GRAPHS 1000

#define NB_C 782                 // coarse buckets: dst>>7, 128 nodes each
#define B1   256                 // blocks in count/scatter phases
#define CHUNK (N_EDGES / B1)     // 6250 (exact)
#define MTOT (NB_C * B1)         // 200192 count-matrix entries

#define LSTR 68   // LDS row stride for fp32 tiles (2-way max aliasing = free)

typedef unsigned int uint32;
typedef unsigned short ushort16;

// float -> bf16 with round-to-nearest-even
static __device__ __forceinline__ ushort16 f2bf(float f) {
    uint32 u = __float_as_uint(f);
    u += 0x7fffu + ((u >> 16) & 1u);
    return (ushort16)(u >> 16);
}
static __device__ __forceinline__ uint32 pk2(float a, float b) {
    return (uint32)f2bf(a) | ((uint32)f2bf(b) << 16);
}
// unpack a bf16x2 word into two floats (lo = even channel, hi = odd channel)
static __device__ __forceinline__ void bf2x(uint32 v, float& lo, float& hi) {
    lo = __uint_as_float(v << 16);
    hi = __uint_as_float(v & 0xffff0000u);
}

// ============ CSR build: two-level counting sort (LDS atomics only) ============

__global__ __launch_bounds__(256) void count_kernel(
    const int* __restrict__ dst, int* __restrict__ M)
{
    __shared__ int cnt[NB_C];
    int b = blockIdx.x, t = threadIdx.x;
    for (int q = t; q < NB_C; q += 256) cnt[q] = 0;
    __syncthreads();
    int e0 = b * CHUNK;
    for (int e = e0 + t; e < e0 + CHUNK; e += 256)
        atomicAdd(&cnt[dst[e] >> 7], 1);
    __syncthreads();
    for (int q = t; q < NB_C; q += 256) M[q * B1 + b] = cnt[q];
}

#define SCAN_B 1024
#define SCAN_NBLK ((MTOT + SCAN_B - 1) / SCAN_B)   // 196

__global__ __launch_bounds__(256) void scanA_kernel(
    const int* __restrict__ in, int* __restrict__ excl, int* __restrict__ bsum)
{
    __shared__ int s[256];
    int b = blockIdx.x, t = threadIdx.x;
    int base = b * SCAN_B + t * 4;
    int v[4];
#pragma unroll
    for (int i = 0; i < 4; ++i) v[i] = (base + i < MTOT) ? in[base + i] : 0;
    int tsum = v[0] + v[1] + v[2] + v[3];
    s[t] = tsum;
    __syncthreads();
    for (int off = 1; off < 256; off <<= 1) {
        int x = (t >= off) ? s[t - off] : 0;
        __syncthreads();
        s[t] += x;
        __syncthreads();
    }
    int run = s[t] - tsum;
#pragma unroll
    for (int i = 0; i < 4; ++i) {
        if (base + i < MTOT) excl[base + i] = run;
        run += v[i];
    }
    if (t == 255) bsum[b] = s[255];
}

__global__ __launch_bounds__(256) void scanB_kernel(int* __restrict__ bsum)
{
    __shared__ int s[256];
    int t = threadIdx.x;
    int v = (t < SCAN_NBLK) ? bsum[t] : 0;
    s[t] = v;
    __syncthreads();
    for (int off = 1; off < 256; off <<= 1) {
        int x = (t >= off) ? s[t - off] : 0;
        __syncthreads();
        s[t] += x;
        __syncthreads();
    }
    if (t < SCAN_NBLK) bsum[t] = s[t] - v;   // exclusive
}

__global__ __launch_bounds__(256) void scanC_kernel(
    const int* __restrict__ excl, const int* __restrict__ bsum,
    int* __restrict__ out)
{
    int b = blockIdx.x, t = threadIdx.x;
    int add = bsum[b];
    int base = b * SCAN_B + t * 4;
#pragma unroll
    for (int i = 0; i < 4; ++i)
        if (base + i < MTOT) out[base + i] = excl[base + i] + add;
}

__global__ __launch_bounds__(256) void scatter_kernel(
    const int* __restrict__ src, const int* __restrict__ dst,
    const int* __restrict__ Ms, uint32* __restrict__ tmp)
{
    __shared__ int cur[NB_C];
    int b = blockIdx.x, t = threadIdx.x;
    for (int q = t; q < NB_C; q += 256) cur[q] = Ms[q * B1 + b];
    __syncthreads();
    int e0 = b * CHUNK;
    for (int e = e0 + t; e < e0 + CHUNK; e += 256) {
        int d = dst[e];
        int q = d >> 7;
        int pos = atomicAdd(&cur[q], 1);
        tmp[pos] = ((uint32)(d & 127) << 17) | (uint32)src[e];
    }
}

__global__ __launch_bounds__(256) void finalize_kernel(
    const uint32* __restrict__ tmp, const int* __restrict__ Ms,
    int* __restrict__ row_off, int* __restrict__ esrc)
{
    __shared__ int cnt[128];
    __shared__ int pref[128];
    __shared__ int cur[128];
    int q = blockIdx.x, t = threadIdx.x;
    int start = Ms[q * B1];
    int end = (q == NB_C - 1) ? N_EDGES : Ms[(q + 1) * B1];

    if (t < 128) cnt[t] = 0;
    __syncthreads();
    for (int e = start + t; e < end; e += 256)
        atomicAdd(&cnt[tmp[e] >> 17], 1);
    __syncthreads();
    if (t < 128) pref[t] = cnt[t];
    __syncthreads();
    for (int off = 1; off < 128; off <<= 1) {
        int x = 0;
        if (t < 128 && t >= off) x = pref[t - off];
        __syncthreads();
        if (t < 128) pref[t] += x;
        __syncthreads();
    }
    if (t < 128) {
        int excl = pref[t] - cnt[t];
        int node = q * 128 + t;
        if (node < N_NODES) row_off[node] = start + excl;
        cur[t] = start + excl;
    }
    if (q == 0 && t == 0) row_off[N_NODES] = N_EDGES;
    __syncthreads();
    for (int e = start + t; e < end; e += 256) {
        uint32 u = tmp[e];
        int pos = atomicAdd(&cur[u >> 17], 1);
        esrc[pos] = (int)(u & 0x1FFFFu);
    }
}

// ============ y(bf16) = h(fp32) @ W  — layer 1 ============
// W (16 KB, shared by all blocks) is read directly from global: it lives in
// the 32 KB per-CU L1 after first touch. LDS holds only the h tile (17.4 KB)
// -> ~6 blocks/CU instead of 4 (33.8 KB) — more waves to hide latency.
template<int IN>
__global__ __launch_bounds__(256) void gemm_kernel(
    const float* __restrict__ h,   // [N, IN] fp32
    const float* __restrict__ W,   // [IN, 64] row-major
    ushort16* __restrict__ y)      // [N, 64] bf16
{
    __shared__ float hs[64 * LSTR];    // [row][k], padded

    const int t = threadIdx.x;
    const int node0 = blockIdx.x * 64;
    const int m = t >> 4;
    const int p = t & 15;

    float4 acc[4];
#pragma unroll
    for (int i = 0; i < 4; ++i) acc[i] = make_float4(0.f, 0.f, 0.f, 0.f);

    for (int kb = 0; kb < IN / 64; ++kb) {
        if (kb) __syncthreads();
        {
            int kc = (t & 15) * 4;
            int rbase = t >> 4;
#pragma unroll
            for (int rr = 0; rr < 4; ++rr) {
                int row = rr * 16 + rbase;
                int node = node0 + row;
                float4 v = make_float4(0.f, 0.f, 0.f, 0.f);
                if (node < N_NODES)
                    v = *(const float4*)&h[(size_t)node * IN + kb * 64 + kc];
                *(float4*)&hs[row * LSTR + kc] = v;
            }
        }
        __syncthreads();

        const float* hb = &hs[(m * 4) * LSTR];
        const float* Wb = W + (size_t)(kb * 64) * 64 + p * 4;
#pragma unroll 4
        for (int kc = 0; kc < 64; kc += 4) {
            float4 hv[4];
#pragma unroll
            for (int i = 0; i < 4; ++i) hv[i] = *(const float4*)&hb[i * LSTR + kc];
            float4 w0 = *(const float4*)&Wb[(kc + 0) * 64];
            float4 w1 = *(const float4*)&Wb[(kc + 1) * 64];
            float4 w2 = *(const float4*)&Wb[(kc + 2) * 64];
            float4 w3 = *(const float4*)&Wb[(kc + 3) * 64];
#pragma unroll
            for (int i = 0; i < 4; ++i) {
                acc[i].x = fmaf(hv[i].x, w0.x, acc[i].x);
                acc[i].y = fmaf(hv[i].x, w0.y, acc[i].y);
                acc[i].z = fmaf(hv[i].x, w0.z, acc[i].z);
                acc[i].w = fmaf(hv[i].x, w0.w, acc[i].w);
                acc[i].x = fmaf(hv[i].y, w1.x, acc[i].x);
                acc[i].y = fmaf(hv[i].y, w1.y, acc[i].y);
                acc[i].z = fmaf(hv[i].y, w1.z, acc[i].z);
                acc[i].w = fmaf(hv[i].y, w1.w, acc[i].w);
                acc[i].x = fmaf(hv[i].z, w2.x, acc[i].x);
                acc[i].y = fmaf(hv[i].z, w2.y, acc[i].y);
                acc[i].z = fmaf(hv[i].z, w2.z, acc[i].z);
                acc[i].w = fmaf(hv[i].z, w2.w, acc[i].w);
                acc[i].x = fmaf(hv[i].w, w3.x, acc[i].x);
                acc[i].y = fmaf(hv[i].w, w3.y, acc[i].y);
                acc[i].z = fmaf(hv[i].w, w3.z, acc[i].z);
                acc[i].w = fmaf(hv[i].w, w3.w, acc[i].w);
            }
        }
    }

#pragma unroll
    for (int i = 0; i < 4; ++i) {
        int node = node0 + m * 4 + i;
        if (node >= N_NODES) continue;
        *(uint2*)&y[(size_t)node * 64 + p * 4] =
            make_uint2(pk2(acc[i].x, acc[i].y), pk2(acc[i].z, acc[i].w));
    }
}

// ============ y(bf16) = h(bf16) @ W  — layers 2/3 (W from L1) ============
__global__ __launch_bounds__(256) void gemm_bf16_kernel(
    const uint32* __restrict__ hb,  // [N, 32] bf16x2 words
    const float* __restrict__ W,    // [64, 64] row-major
    ushort16* __restrict__ y)       // [N, 64] bf16
{
    __shared__ float hs[64 * LSTR];

    const int t = threadIdx.x;
    const int node0 = blockIdx.x * 64;

    // ---- stage h tile from bf16 (unpack at staging) ----
    {
        int w = t & 7;
        int rbase = t >> 3;               // 0..31
#pragma unroll
        for (int rr = 0; rr < 2; ++rr) {
            int row = rr * 32 + rbase;
            int node = node0 + row;
            uint4 v = make_uint4(0u, 0u, 0u, 0u);
            if (node < N_NODES)
                v = *(const uint4*)&hb[(size_t)node * 32 + w * 4];
            float f[8];
            bf2x(v.x, f[0], f[1]);
            bf2x(v.y, f[2], f[3]);
            bf2x(v.z, f[4], f[5]);
            bf2x(v.w, f[6], f[7]);
            float* o = &hs[row * LSTR + w * 8];
            *(float4*)o       = make_float4(f[0], f[1], f[2], f[3]);
            *(float4*)(o + 4) = make_float4(f[4], f[5], f[6], f[7]);
        }
    }
    __syncthreads();

    const int m = t >> 4;
    const int p = t & 15;
    float4 acc[4];
#pragma unroll
    for (int i = 0; i < 4; ++i) acc[i] = make_float4(0.f, 0.f, 0.f, 0.f);

    const float* hbp = &hs[(m * 4) * LSTR];
    const float* Wb = W + p * 4;
#pragma unroll 4
    for (int kc = 0; kc < 64; kc += 4) {
        float4 hv[4];
#pragma unroll
        for (int i = 0; i < 4; ++i) hv[i] = *(const float4*)&hbp[i * LSTR + kc];
        float4 w0 = *(const float4*)&Wb[(kc + 0) * 64];
        float4 w1 = *(const float4*)&Wb[(kc + 1) * 64];
        float4 w2 = *(const float4*)&Wb[(kc + 2) * 64];
        float4 w3 = *(const float4*)&Wb[(kc + 3) * 64];
#pragma unroll
        for (int i = 0; i < 4; ++i) {
            acc[i].x = fmaf(hv[i].x, w0.x, acc[i].x);
            acc[i].y = fmaf(hv[i].x, w0.y, acc[i].y);
            acc[i].z = fmaf(hv[i].x, w0.z, acc[i].z);
            acc[i].w = fmaf(hv[i].x, w0.w, acc[i].w);
            acc[i].x = fmaf(hv[i].y, w1.x, acc[i].x);
            acc[i].y = fmaf(hv[i].y, w1.y, acc[i].y);
            acc[i].z = fmaf(hv[i].y, w1.z, acc[i].z);
            acc[i].w = fmaf(hv[i].y, w1.w, acc[i].w);
            acc[i].x = fmaf(hv[i].z, w2.x, acc[i].x);
            acc[i].y = fmaf(hv[i].z, w2.y, acc[i].y);
            acc[i].z = fmaf(hv[i].z, w2.z, acc[i].z);
            acc[i].w = fmaf(hv[i].z, w2.w, acc[i].w);
            acc[i].x = fmaf(hv[i].w, w3.x, acc[i].x);
            acc[i].y = fmaf(hv[i].w, w3.y, acc[i].y);
            acc[i].z = fmaf(hv[i].w, w3.z, acc[i].z);
            acc[i].w = fmaf(hv[i].w, w3.w, acc[i].w);
        }
    }

#pragma unroll
    for (int i = 0; i < 4; ++i) {
        int node = node0 + m * 4 + i;
        if (node >= N_NODES) continue;
        *(uint2*)&y[(size_t)node * 64 + p * 4] =
            make_uint2(pk2(acc[i].x, acc[i].y), pk2(acc[i].z, acc[i].w));
    }
}

// ============ CSR gather-sum + fused GIN epilogue -> h(bf16) ============
// Wave = 4 nodes. Lane l: g = l>>4 (node), j = (l>>3)&1 (edge slot),
// w = l&7 (uint4 chunk of the 128 B row). 16 gathers in flight per wave;
// single shfl_xor(8) reduction; epilogue once per wave for 4 nodes.
__global__ __launch_bounds__(256) void aggregate_kernel(
    const uint32* __restrict__ y,      // [N, 32] bf16x2 words
    const int* __restrict__ row_off,   // [N+1]
    const int* __restrict__ esrc,      // [E]
    const float* __restrict__ b,       // [64]
    const float* __restrict__ eps_p,   // [1]
    uint32* __restrict__ outb)         // [N, 32] bf16x2 words
{
    int lane = threadIdx.x & 63;
    int wave = threadIdx.x >> 6;
    int g = lane >> 4;        // node sub-index 0..3
    int j = (lane >> 3) & 1;  // edge slot
    int w = lane & 7;         // 16B chunk of row
    int node = blockIdx.x * 16 + wave * 4 + g;   // grid covers N exactly

    int s0 = row_off[node], s1 = row_off[node + 1];
    float a[8], c[8];
#pragma unroll
    for (int i = 0; i < 8; ++i) { a[i] = 0.f; c[i] = 0.f; }

    const uint32* yw = y + (size_t)w * 4;
    int e = s0 + j;
    for (; e + 2 < s1; e += 4) {
        int i0 = esrc[e];
        int i1 = esrc[e + 2];
        uint4 v0 = *(const uint4*)&yw[(size_t)i0 * 32];
        uint4 v1 = *(const uint4*)&yw[(size_t)i1 * 32];
        float lo, hi;
        bf2x(v0.x, lo, hi); a[0] += lo; a[1] += hi;
        bf2x(v0.y, lo, hi); a[2] += lo; a[3] += hi;
        bf2x(v0.z, lo, hi); a[4] += lo; a[5] += hi;
        bf2x(v0.w, lo, hi); a[6] += lo; a[7] += hi;
        bf2x(v1.x, lo, hi); c[0] += lo; c[1] += hi;
        bf2x(v1.y, lo, hi); c[2] += lo; c[3] += hi;
        bf2x(v1.z, lo, hi); c[4] += lo; c[5] += hi;
        bf2x(v1.w, lo, hi); c[6] += lo; c[7] += hi;
    }
    if (e < s1) {
        int i0 = esrc[e];
        uint4 v0 = *(const uint4*)&yw[(size_t)i0 * 32];
        float lo, hi;
        bf2x(v0.x, lo, hi); a[0] += lo; a[1] += hi;
        bf2x(v0.y, lo, hi); a[2] += lo; a[3] += hi;
        bf2x(v0.z, lo, hi); a[4] += lo; a[5] += hi;
        bf2x(v0.w, lo, hi); a[6] += lo; a[7] += hi;
    }
#pragma unroll
    for (int i = 0; i < 8; ++i) {
        a[i] += c[i];
        a[i] += __shfl_xor(a[i], 8);   // combine the two slots (j)
    }

    if (j == 0) {
        uint4 sv = *(const uint4*)&yw[(size_t)node * 32];
        float s[8];
        bf2x(sv.x, s[0], s[1]);
        bf2x(sv.y, s[2], s[3]);
        bf2x(sv.z, s[4], s[5]);
        bf2x(sv.w, s[6], s[7]);
        float ep1 = 1.0f + eps_p[0];
        float4 b0 = *(const float4*)&b[w * 8];
        float4 b1 = *(const float4*)&b[w * 8 + 4];
        float r0 = fmaxf(fmaf(ep1, s[0], a[0]) + b0.x, 0.0f);
        float r1 = fmaxf(fmaf(ep1, s[1], a[1]) + b0.y, 0.0f);
        float r2 = fmaxf(fmaf(ep1, s[2], a[2]) + b0.z, 0.0f);
        float r3 = fmaxf(fmaf(ep1, s[3], a[3]) + b0.w, 0.0f);
        float r4 = fmaxf(fmaf(ep1, s[4], a[4]) + b1.x, 0.0f);
        float r5 = fmaxf(fmaf(ep1, s[5], a[5]) + b1.y, 0.0f);
        float r6 = fmaxf(fmaf(ep1, s[6], a[6]) + b1.z, 0.0f);
        float r7 = fmaxf(fmaf(ep1, s[7], a[7]) + b1.w, 0.0f);
        *(uint4*)&outb[(size_t)node * 32 + w * 4] =
            make_uint4(pk2(r0, r1), pk2(r2, r3), pk2(r4, r5), pk2(r6, r7));
    }
}

// ============ mean-pool (sorted batch, binary search, bf16 h) + head MLP ============
__global__ __launch_bounds__(256) void pool_head_kernel(
    const uint32* __restrict__ hb,    // [N, 32] bf16x2 words
    const int* __restrict__ batch,    // [N], sorted
    const float* __restrict__ Wf,     // [64, 10]
    const float* __restrict__ bfv,    // [10]
    const float* __restrict__ Wl,     // [10]
    const float* __restrict__ blv,    // [1]
    float* __restrict__ out)          // [G]
{
    __shared__ float red[4][64];
    __shared__ float pooled[64];
    __shared__ float hid[10];
    int g = blockIdx.x;
    int t = threadIdx.x;
    int lo = 0, hi = N_NODES;
    while (lo < hi) { int mid = (lo + hi) >> 1; if (batch[mid] < g) lo = mid + 1; else hi = mid; }
    int start = lo;
    hi = N_NODES;
    while (lo < hi) { int mid = (lo + hi) >> 1; if (batch[mid] < g + 1) lo = mid + 1; else hi = mid; }
    int end = lo;

    int c = t & 63, nl = t >> 6;
    int wd = c >> 1, odd = c & 1;
    float acc = 0.0f;
    for (int i = start + nl; i < end; i += 4) {
        uint32 u = hb[(size_t)i * 32 + wd];
        acc += __uint_as_float(odd ? (u & 0xffff0000u) : (u << 16));
    }
    red[nl][c] = acc;
    __syncthreads();
    if (t < 64) {
        float cnt = (float)(end - start);
        float inv = 1.0f / fmaxf(cnt, 1.0f);
        pooled[t] = (red[0][t] + red[1][t] + red[2][t] + red[3][t]) * inv;
    }
    __syncthreads();
    if (t < 10) {
        float s = bfv[t];
#pragma unroll
        for (int k = 0; k < 64; ++k) s = fmaf(pooled[k], Wf[k * 10 + t], s);
        hid[t] = fmaxf(s, 0.0f);
    }
    __syncthreads();
    if (t == 0) {
        float s = blv[0];
#pragma unroll
        for (int j = 0; j < 10; ++j) s = fmaf(hid[j], Wl[j], s);
        out[g] = s;
    }
}

extern "C" void kernel_launch(void* const* d_in, const int* in_sizes, int n_in,
                              void* d_out, int out_size, void* d_ws, size_t ws_size,
                              hipStream_t stream)
{
    const float* x     = (const float*)d_in[0];
    const int*   ei    = (const int*)  d_in[1];
    const int*   src   = ei;               // edge_index[0]
    const int*   dst   = ei + N_EDGES;     // edge_index[1]
    const int*   batch = (const int*)  d_in[2];
    const float* W1    = (const float*)d_in[3];
    const float* b1    = (const float*)d_in[4];
    const float* W2    = (const float*)d_in[5];
    const float* b2    = (const float*)d_in[6];
    const float* W3    = (const float*)d_in[7];
    const float* b3    = (const float*)d_in[8];
    const float* Wf    = (const float*)d_in[9];
    const float* bfv   = (const float*)d_in[10];
    const float* Wl    = (const float*)d_in[11];
    const float* blv   = (const float*)d_in[12];
    const float* eps1  = (const float*)d_in[13];
    const float* eps2  = (const float*)d_in[14];
    const float* eps3  = (const float*)d_in[15];

    // ---- workspace layout (two ping-pong bf16 node arrays) ----
    ushort16* ybA = (ushort16*)d_ws;                       // N*64 bf16
    ushort16* ybB = ybA + (size_t)N_NODES * 64;            // N*64 bf16
    int*   ints = (int*)(ybB + (size_t)N_NODES * 64);
    int*   M       = ints;                      // MTOT
    int*   Mex     = M + MTOT;                  // MTOT
    int*   Ms      = Mex + MTOT;                // MTOT
    int*   bsum    = Ms + MTOT;                 // 256
    int*   row_off = bsum + 256;                // N+1
    int*   esrc    = row_off + N_NODES + 1;     // E
    uint32* tmp    = (uint32*)(esrc + N_EDGES); // E

    // ---- build CSR: two-level counting sort, LDS atomics only ----
    count_kernel<<<B1, 256, 0, stream>>>(dst, M);
    scanA_kernel<<<SCAN_NBLK, 256, 0, stream>>>(M, Mex, bsum);
    scanB_kernel<<<1, 256, 0, stream>>>(bsum);
    scanC_kernel<<<SCAN_NBLK, 256, 0, stream>>>(Mex, bsum, Ms);
    scatter_kernel<<<B1, 256, 0, stream>>>(src, dst, Ms, tmp);
    finalize_kernel<<<NB_C, 256, 0, stream>>>(tmp, Ms, row_off, esrc);

    const int gemm_blk = (N_NODES + 63) / 64;    // 1563
    const int agg_blk  = N_NODES / 16;           // 6250 (exact: 16 nodes/block)

    // ---- layer 1: y1 = x@W1 (ybA); h1 = GIN(y1) (ybB, bf16) ----
    gemm_kernel<128><<<gemm_blk, 256, 0, stream>>>(x, W1, ybA);
    aggregate_kernel<<<agg_blk, 256, 0, stream>>>(
        (const uint32*)ybA, row_off, esrc, b1, eps1, (uint32*)ybB);

    // ---- layer 2: y2 = h1@W2 (ybA); h2 = GIN(y2) (ybB) ----
    gemm_bf16_kernel<<<gemm_blk, 256, 0, stream>>>((const uint32*)ybB, W2, ybA);
    aggregate_kernel<<<agg_blk, 256, 0, stream>>>(
        (const uint32*)ybA, row_off, esrc, b2, eps2, (uint32*)ybB);

    // ---- layer 3: y3 = h2@W3 (ybA); h3 = GIN(y3) (ybB) ----
    gemm_bf16_kernel<<<gemm_blk, 256, 0, stream>>>((const uint32*)ybB, W3, ybA);
    aggregate_kernel<<<agg_blk, 256, 0, stream>>>(
        (const uint32*)ybA, row_off, esrc, b3, eps3, (uint32*)ybB);

    // ---- pool + head ----
    pool_head_kernel<<<N_GRAPHS, 256, 0, stream>>>(
        (const uint32*)ybB, batch, Wf, bfv, Wl, blv, (float*)d_out);
}

// Round 16
// 330.383 us; speedup vs baseline: 1.0782x; 1.0676x over previous
//
#include <hip/hip_runtime.h>

#define N_NODES 100000
#define N_EDGES 1600000
#define N_GRAPHS 1000

#define NB_C 782                 // coarse buckets: dst>>7, 128 nodes each
#define B1   256                 // blocks in count/scatter phases
#define CHUNK (N_EDGES / B1)     // 6250 (exact)
#define MTOT (NB_C * B1)         // 200192 count-matrix entries

typedef unsigned int uint32;
typedef unsigned short ushort16;
typedef __attribute__((ext_vector_type(8))) short short8;   // 8 bf16 (4 VGPRs)
typedef __attribute__((ext_vector_type(4))) float f32x4;    // MFMA C/D

// float -> bf16 with round-to-nearest-even
static __device__ __forceinline__ ushort16 f2bf(float f) {
    uint32 u = __float_as_uint(f);
    u += 0x7fffu + ((u >> 16) & 1u);
    return (ushort16)(u >> 16);
}
static __device__ __forceinline__ uint32 pk2(float a, float b) {
    return (uint32)f2bf(a) | ((uint32)f2bf(b) << 16);
}
// unpack a bf16x2 word into two floats
static __device__ __forceinline__ void bf2x(uint32 v, float& lo, float& hi) {
    lo = __uint_as_float(v << 16);
    hi = __uint_as_float(v & 0xffff0000u);
}

union CV8 { uint4 u; short8 s; };

// ============ weight pre-pass: Wt[j][k] = bf16(W[k][j]) ============
__global__ __launch_bounds__(256) void convw_kernel(
    const float* __restrict__ W1, const float* __restrict__ W2,
    const float* __restrict__ W3,
    ushort16* __restrict__ W1t, ushort16* __restrict__ W2t,
    ushort16* __restrict__ W3t)
{
    int t = threadIdx.x;
    if (blockIdx.x == 0) {
        for (int i = t; i < 64 * 128; i += 256) {
            int j = i >> 7, k = i & 127;          // W1t[j][k] (64 x 128)
            W1t[i] = f2bf(W1[k * 64 + j]);
        }
    } else if (blockIdx.x == 1) {
        for (int i = t; i < 64 * 64; i += 256) {
            int j = i >> 6, k = i & 63;
            W2t[i] = f2bf(W2[k * 64 + j]);
        }
    } else {
        for (int i = t; i < 64 * 64; i += 256) {
            int j = i >> 6, k = i & 63;
            W3t[i] = f2bf(W3[k * 64 + j]);
        }
    }
}

// ============ CSR build: two-level counting sort (LDS atomics only) ============

__global__ __launch_bounds__(256) void count_kernel(
    const int* __restrict__ dst, int* __restrict__ M)
{
    __shared__ int cnt[NB_C];
    int b = blockIdx.x, t = threadIdx.x;
    for (int q = t; q < NB_C; q += 256) cnt[q] = 0;
    __syncthreads();
    int e0 = b * CHUNK;
    for (int e = e0 + t; e < e0 + CHUNK; e += 256)
        atomicAdd(&cnt[dst[e] >> 7], 1);
    __syncthreads();
    for (int q = t; q < NB_C; q += 256) M[q * B1 + b] = cnt[q];
}

#define SCAN_B 1024
#define SCAN_NBLK ((MTOT + SCAN_B - 1) / SCAN_B)   // 196

__global__ __launch_bounds__(256) void scanA_kernel(
    const int* __restrict__ in, int* __restrict__ excl, int* __restrict__ bsum)
{
    __shared__ int s[256];
    int b = blockIdx.x, t = threadIdx.x;
    int base = b * SCAN_B + t * 4;
    int v[4];
#pragma unroll
    for (int i = 0; i < 4; ++i) v[i] = (base + i < MTOT) ? in[base + i] : 0;
    int tsum = v[0] + v[1] + v[2] + v[3];
    s[t] = tsum;
    __syncthreads();
    for (int off = 1; off < 256; off <<= 1) {
        int x = (t >= off) ? s[t - off] : 0;
        __syncthreads();
        s[t] += x;
        __syncthreads();
    }
    int run = s[t] - tsum;
#pragma unroll
    for (int i = 0; i < 4; ++i) {
        if (base + i < MTOT) excl[base + i] = run;
        run += v[i];
    }
    if (t == 255) bsum[b] = s[255];
}

__global__ __launch_bounds__(256) void scanB_kernel(int* __restrict__ bsum)
{
    __shared__ int s[256];
    int t = threadIdx.x;
    int v = (t < SCAN_NBLK) ? bsum[t] : 0;
    s[t] = v;
    __syncthreads();
    for (int off = 1; off < 256; off <<= 1) {
        int x = (t >= off) ? s[t - off] : 0;
        __syncthreads();
        s[t] += x;
        __syncthreads();
    }
    if (t < SCAN_NBLK) bsum[t] = s[t] - v;   // exclusive
}

__global__ __launch_bounds__(256) void scanC_kernel(
    const int* __restrict__ excl, const int* __restrict__ bsum,
    int* __restrict__ out)
{
    int b = blockIdx.x, t = threadIdx.x;
    int add = bsum[b];
    int base = b * SCAN_B + t * 4;
#pragma unroll
    for (int i = 0; i < 4; ++i)
        if (base + i < MTOT) out[base + i] = excl[base + i] + add;
}

__global__ __launch_bounds__(256) void scatter_kernel(
    const int* __restrict__ src, const int* __restrict__ dst,
    const int* __restrict__ Ms, uint32* __restrict__ tmp)
{
    __shared__ int cur[NB_C];
    int b = blockIdx.x, t = threadIdx.x;
    for (int q = t; q < NB_C; q += 256) cur[q] = Ms[q * B1 + b];
    __syncthreads();
    int e0 = b * CHUNK;
    for (int e = e0 + t; e < e0 + CHUNK; e += 256) {
        int d = dst[e];
        int q = d >> 7;
        int pos = atomicAdd(&cur[q], 1);
        tmp[pos] = ((uint32)(d & 127) << 17) | (uint32)src[e];
    }
}

__global__ __launch_bounds__(256) void finalize_kernel(
    const uint32* __restrict__ tmp, const int* __restrict__ Ms,
    int* __restrict__ row_off, int* __restrict__ esrc)
{
    __shared__ int cnt[128];
    __shared__ int pref[128];
    __shared__ int cur[128];
    int q = blockIdx.x, t = threadIdx.x;
    int start = Ms[q * B1];
    int end = (q == NB_C - 1) ? N_EDGES : Ms[(q + 1) * B1];

    if (t < 128) cnt[t] = 0;
    __syncthreads();
    for (int e = start + t; e < end; e += 256)
        atomicAdd(&cnt[tmp[e] >> 17], 1);
    __syncthreads();
    if (t < 128) pref[t] = cnt[t];
    __syncthreads();
    for (int off = 1; off < 128; off <<= 1) {
        int x = 0;
        if (t < 128 && t >= off) x = pref[t - off];
        __syncthreads();
        if (t < 128) pref[t] += x;
        __syncthreads();
    }
    if (t < 128) {
        int excl = pref[t] - cnt[t];
        int node = q * 128 + t;
        if (node < N_NODES) row_off[node] = start + excl;
        cur[t] = start + excl;
    }
    if (q == 0 && t == 0) row_off[N_NODES] = N_EDGES;
    __syncthreads();
    for (int e = start + t; e < end; e += 256) {
        uint32 u = tmp[e];
        int pos = atomicAdd(&cur[u >> 17], 1);
        esrc[pos] = (int)(u & 0x1FFFFu);
    }
}

// ============ MFMA GEMM, layer 1: y(bf16) = x(fp32->bf16) @ W1 ============
// 1 wave = 16 nodes x 64 outs, K=128. No LDS, no barriers. Verified layouts:
// A[m=lane&15][k=quad*8+j]; B from Wt[n][k] (B^T pattern, m97);
// D: col=lane&15, row=quad*4+reg (m89/m91).
__global__ __launch_bounds__(256) void gemm1_mfma_kernel(
    const float* __restrict__ x,       // [N, 128] fp32
    const ushort16* __restrict__ Wt,   // [64][128] bf16 (Wt[j][k] = W1[k][j])
    ushort16* __restrict__ y)          // [N, 64] bf16
{
    int lane = threadIdx.x & 63;
    int wave = threadIdx.x >> 6;
    int col = lane & 15, quad = lane >> 4;
    int node0 = blockIdx.x * 64 + wave * 16;
    int anode = node0 + col;

    short8 a[4];
    if (anode < N_NODES) {
        const float* xr = &x[(size_t)anode * 128 + quad * 8];
#pragma unroll
        for (int s = 0; s < 4; ++s) {
            float4 v0 = *(const float4*)&xr[s * 32];
            float4 v1 = *(const float4*)&xr[s * 32 + 4];
            CV8 cv;
            cv.u = make_uint4(pk2(v0.x, v0.y), pk2(v0.z, v0.w),
                              pk2(v1.x, v1.y), pk2(v1.z, v1.w));
            a[s] = cv.s;
        }
    } else {
        short8 z = {0, 0, 0, 0, 0, 0, 0, 0};
#pragma unroll
        for (int s = 0; s < 4; ++s) a[s] = z;
    }

    f32x4 acc[4];
#pragma unroll
    for (int nt = 0; nt < 4; ++nt)
#pragma unroll
        for (int r = 0; r < 4; ++r) acc[nt][r] = 0.0f;

#pragma unroll
    for (int nt = 0; nt < 4; ++nt) {
        const ushort16* wr = &Wt[(size_t)(nt * 16 + col) * 128 + quad * 8];
#pragma unroll
        for (int s = 0; s < 4; ++s) {
            short8 b = *(const short8*)&wr[s * 32];
            acc[nt] = __builtin_amdgcn_mfma_f32_16x16x32_bf16(a[s], b, acc[nt], 0, 0, 0);
        }
    }

#pragma unroll
    for (int nt = 0; nt < 4; ++nt)
#pragma unroll
        for (int r = 0; r < 4; ++r) {
            int node = node0 + quad * 4 + r;
            if (node < N_NODES)
                y[(size_t)node * 64 + nt * 16 + col] = f2bf(acc[nt][r]);
        }
}

// ============ MFMA GEMM, layers 2/3: y(bf16) = h(bf16) @ W ============
__global__ __launch_bounds__(256) void gemm_mfma_kernel(
    const ushort16* __restrict__ hb,   // [N, 64] bf16
    const ushort16* __restrict__ Wt,   // [64][64] bf16 (Wt[j][k] = W[k][j])
    ushort16* __restrict__ y)          // [N, 64] bf16
{
    int lane = threadIdx.x & 63;
    int wave = threadIdx.x >> 6;
    int col = lane & 15, quad = lane >> 4;
    int node0 = blockIdx.x * 64 + wave * 16;
    int anode = node0 + col;

    short8 a0, a1;
    if (anode < N_NODES) {
        a0 = *(const short8*)&hb[(size_t)anode * 64 + quad * 8];
        a1 = *(const short8*)&hb[(size_t)anode * 64 + 32 + quad * 8];
    } else {
        short8 z = {0, 0, 0, 0, 0, 0, 0, 0};
        a0 = z; a1 = z;
    }

    f32x4 acc[4];
#pragma unroll
    for (int nt = 0; nt < 4; ++nt)
#pragma unroll
        for (int r = 0; r < 4; ++r) acc[nt][r] = 0.0f;

#pragma unroll
    for (int nt = 0; nt < 4; ++nt) {
        const ushort16* wr = &Wt[(size_t)(nt * 16 + col) * 64 + quad * 8];
        short8 b0 = *(const short8*)&wr[0];
        short8 b1 = *(const short8*)&wr[32];
        acc[nt] = __builtin_amdgcn_mfma_f32_16x16x32_bf16(a0, b0, acc[nt], 0, 0, 0);
        acc[nt] = __builtin_amdgcn_mfma_f32_16x16x32_bf16(a1, b1, acc[nt], 0, 0, 0);
    }

#pragma unroll
    for (int nt = 0; nt < 4; ++nt)
#pragma unroll
        for (int r = 0; r < 4; ++r) {
            int node = node0 + quad * 4 + r;
            if (node < N_NODES)
                y[(size_t)node * 64 + nt * 16 + col] = f2bf(acc[nt][r]);
        }
}

// ============ CSR gather-sum + fused GIN epilogue -> h(bf16) ============
// Wave = 4 nodes. Lane l: g = l>>4 (node), j = (l>>3)&1 (edge slot),
// w = l&7 (uint4 chunk of the 128 B row). 16 gathers in flight per wave;
// single shfl_xor(8) reduction; epilogue once per wave for 4 nodes.
__global__ __launch_bounds__(256) void aggregate_kernel(
    const uint32* __restrict__ y,      // [N, 32] bf16x2 words
    const int* __restrict__ row_off,   // [N+1]
    const int* __restrict__ esrc,      // [E]
    const float* __restrict__ b,       // [64]
    const float* __restrict__ eps_p,   // [1]
    uint32* __restrict__ outb)         // [N, 32] bf16x2 words
{
    int lane = threadIdx.x & 63;
    int wave = threadIdx.x >> 6;
    int g = lane >> 4;        // node sub-index 0..3
    int j = (lane >> 3) & 1;  // edge slot
    int w = lane & 7;         // 16B chunk of row
    int node = blockIdx.x * 16 + wave * 4 + g;   // grid covers N exactly

    int s0 = row_off[node], s1 = row_off[node + 1];
    float a[8], c[8];
#pragma unroll
    for (int i = 0; i < 8; ++i) { a[i] = 0.f; c[i] = 0.f; }

    const uint32* yw = y + (size_t)w * 4;
    int e = s0 + j;
    for (; e + 2 < s1; e += 4) {
        int i0 = esrc[e];
        int i1 = esrc[e + 2];
        uint4 v0 = *(const uint4*)&yw[(size_t)i0 * 32];
        uint4 v1 = *(const uint4*)&yw[(size_t)i1 * 32];
        float lo, hi;
        bf2x(v0.x, lo, hi); a[0] += lo; a[1] += hi;
        bf2x(v0.y, lo, hi); a[2] += lo; a[3] += hi;
        bf2x(v0.z, lo, hi); a[4] += lo; a[5] += hi;
        bf2x(v0.w, lo, hi); a[6] += lo; a[7] += hi;
        bf2x(v1.x, lo, hi); c[0] += lo; c[1] += hi;
        bf2x(v1.y, lo, hi); c[2] += lo; c[3] += hi;
        bf2x(v1.z, lo, hi); c[4] += lo; c[5] += hi;
        bf2x(v1.w, lo, hi); c[6] += lo; c[7] += hi;
    }
    if (e < s1) {
        int i0 = esrc[e];
        uint4 v0 = *(const uint4*)&yw[(size_t)i0 * 32];
        float lo, hi;
        bf2x(v0.x, lo, hi); a[0] += lo; a[1] += hi;
        bf2x(v0.y, lo, hi); a[2] += lo; a[3] += hi;
        bf2x(v0.z, lo, hi); a[4] += lo; a[5] += hi;
        bf2x(v0.w, lo, hi); a[6] += lo; a[7] += hi;
    }
#pragma unroll
    for (int i = 0; i < 8; ++i) {
        a[i] += c[i];
        a[i] += __shfl_xor(a[i], 8);   // combine the two slots (j)
    }

    if (j == 0) {
        uint4 sv = *(const uint4*)&yw[(size_t)node * 32];
        float s[8];
        bf2x(sv.x, s[0], s[1]);
        bf2x(sv.y, s[2], s[3]);
        bf2x(sv.z, s[4], s[5]);
        bf2x(sv.w, s[6], s[7]);
        float ep1 = 1.0f + eps_p[0];
        float4 b0 = *(const float4*)&b[w * 8];
        float4 b1 = *(const float4*)&b[w * 8 + 4];
        float r0 = fmaxf(fmaf(ep1, s[0], a[0]) + b0.x, 0.0f);
        float r1 = fmaxf(fmaf(ep1, s[1], a[1]) + b0.y, 0.0f);
        float r2 = fmaxf(fmaf(ep1, s[2], a[2]) + b0.z, 0.0f);
        float r3 = fmaxf(fmaf(ep1, s[3], a[3]) + b0.w, 0.0f);
        float r4 = fmaxf(fmaf(ep1, s[4], a[4]) + b1.x, 0.0f);
        float r5 = fmaxf(fmaf(ep1, s[5], a[5]) + b1.y, 0.0f);
        float r6 = fmaxf(fmaf(ep1, s[6], a[6]) + b1.z, 0.0f);
        float r7 = fmaxf(fmaf(ep1, s[7], a[7]) + b1.w, 0.0f);
        *(uint4*)&outb[(size_t)node * 32 + w * 4] =
            make_uint4(pk2(r0, r1), pk2(r2, r3), pk2(r4, r5), pk2(r6, r7));
    }
}

// ============ mean-pool (sorted batch, binary search, bf16 h) + head MLP ============
__global__ __launch_bounds__(256) void pool_head_kernel(
    const uint32* __restrict__ hb,    // [N, 32] bf16x2 words
    const int* __restrict__ batch,    // [N], sorted
    const float* __restrict__ Wf,     // [64, 10]
    const float* __restrict__ bfv,    // [10]
    const float* __restrict__ Wl,     // [10]
    const float* __restrict__ blv,    // [1]
    float* __restrict__ out)          // [G]
{
    __shared__ float red[4][64];
    __shared__ float pooled[64];
    __shared__ float hid[10];
    int g = blockIdx.x;
    int t = threadIdx.x;
    int lo = 0, hi = N_NODES;
    while (lo < hi) { int mid = (lo + hi) >> 1; if (batch[mid] < g) lo = mid + 1; else hi = mid; }
    int start = lo;
    hi = N_NODES;
    while (lo < hi) { int mid = (lo + hi) >> 1; if (batch[mid] < g + 1) lo = mid + 1; else hi = mid; }
    int end = lo;

    int c = t & 63, nl = t >> 6;
    int wd = c >> 1, odd = c & 1;
    float acc = 0.0f;
    for (int i = start + nl; i < end; i += 4) {
        uint32 u = hb[(size_t)i * 32 + wd];
        acc += __uint_as_float(odd ? (u & 0xffff0000u) : (u << 16));
    }
    red[nl][c] = acc;
    __syncthreads();
    if (t < 64) {
        float cnt = (float)(end - start);
        float inv = 1.0f / fmaxf(cnt, 1.0f);
        pooled[t] = (red[0][t] + red[1][t] + red[2][t] + red[3][t]) * inv;
    }
    __syncthreads();
    if (t < 10) {
        float s = bfv[t];
#pragma unroll
        for (int k = 0; k < 64; ++k) s = fmaf(pooled[k], Wf[k * 10 + t], s);
        hid[t] = fmaxf(s, 0.0f);
    }
    __syncthreads();
    if (t == 0) {
        float s = blv[0];
#pragma unroll
        for (int j = 0; j < 10; ++j) s = fmaf(hid[j], Wl[j], s);
        out[g] = s;
    }
}

extern "C" void kernel_launch(void* const* d_in, const int* in_sizes, int n_in,
                              void* d_out, int out_size, void* d_ws, size_t ws_size,
                              hipStream_t stream)
{
    const float* x     = (const float*)d_in[0];
    const int*   ei    = (const int*)  d_in[1];
    const int*   src   = ei;               // edge_index[0]
    const int*   dst   = ei + N_EDGES;     // edge_index[1]
    const int*   batch = (const int*)  d_in[2];
    const float* W1    = (const float*)d_in[3];
    const float* b1    = (const float*)d_in[4];
    const float* W2    = (const float*)d_in[5];
    const float* b2    = (const float*)d_in[6];
    const float* W3    = (const float*)d_in[7];
    const float* b3    = (const float*)d_in[8];
    const float* Wf    = (const float*)d_in[9];
    const float* bfv   = (const float*)d_in[10];
    const float* Wl    = (const float*)d_in[11];
    const float* blv   = (const float*)d_in[12];
    const float* eps1  = (const float*)d_in[13];
    const float* eps2  = (const float*)d_in[14];
    const float* eps3  = (const float*)d_in[15];

    // ---- workspace layout ----
    ushort16* ybA = (ushort16*)d_ws;                       // N*64 bf16
    ushort16* ybB = ybA + (size_t)N_NODES * 64;            // N*64 bf16
    int*   ints = (int*)(ybB + (size_t)N_NODES * 64);
    int*   M       = ints;                      // MTOT
    int*   Mex     = M + MTOT;                  // MTOT
    int*   Ms      = Mex + MTOT;                // MTOT
    int*   bsum    = Ms + MTOT;                 // 256
    int*   row_off = bsum + 256;                // N+1
    int*   esrc    = row_off + N_NODES + 1;     // E
    uint32* tmp    = (uint32*)(esrc + N_EDGES); // E
    ushort16* W1t = (ushort16*)(((uintptr_t)(tmp + N_EDGES) + 255) & ~(uintptr_t)255);
    ushort16* W2t = W1t + 64 * 128;
    ushort16* W3t = W2t + 64 * 64;

    const int gemm_blk = (N_NODES + 63) / 64;    // 1563
    const int agg_blk  = N_NODES / 16;           // 6250 (exact: 16 nodes/block)

    // ---- weight pre-pass (bf16, transposed) ----
    convw_kernel<<<3, 256, 0, stream>>>(W1, W2, W3, W1t, W2t, W3t);

    // ---- build CSR: two-level counting sort, LDS atomics only ----
    count_kernel<<<B1, 256, 0, stream>>>(dst, M);
    scanA_kernel<<<SCAN_NBLK, 256, 0, stream>>>(M, Mex, bsum);
    scanB_kernel<<<1, 256, 0, stream>>>(bsum);
    scanC_kernel<<<SCAN_NBLK, 256, 0, stream>>>(Mex, bsum, Ms);
    scatter_kernel<<<B1, 256, 0, stream>>>(src, dst, Ms, tmp);
    finalize_kernel<<<NB_C, 256, 0, stream>>>(tmp, Ms, row_off, esrc);

    // ---- layer 1: y1 = x@W1 (ybA, MFMA); h1 = GIN(y1) (ybB) ----
    gemm1_mfma_kernel<<<gemm_blk, 256, 0, stream>>>(x, W1t, ybA);
    aggregate_kernel<<<agg_blk, 256, 0, stream>>>(
        (const uint32*)ybA, row_off, esrc, b1, eps1, (uint32*)ybB);

    // ---- layer 2 ----
    gemm_mfma_kernel<<<gemm_blk, 256, 0, stream>>>(ybB, W2t, ybA);
    aggregate_kernel<<<agg_blk, 256, 0, stream>>>(
        (const uint32*)ybA, row_off, esrc, b2, eps2, (uint32*)ybB);

    // ---- layer 3 ----
    gemm_mfma_kernel<<<gemm_blk, 256, 0, stream>>>(ybB, W3t, ybA);
    aggregate_kernel<<<agg_blk, 256, 0, stream>>>(
        (const uint32*)ybA, row_off, esrc, b3, eps3, (uint32*)ybB);

    // ---- pool + head ----
    pool_head_kernel<<<N_GRAPHS, 256, 0, stream>>>(
        (const uint32*)ybB, batch, Wf, bfv, Wl, blv, (float*)d_out);
}